// Round 6
// baseline (94.662 us; speedup 1.0000x reference)
//
#include <hip/hip_runtime.h>

// 2-layer dense GAT, B=32, N=1024, all fp32. L1: H=3,F=4,O=2 -> ws. L2: H=1,F=6,O=4 -> out.
//
// Round-6: latency-bound fixes.
//  * max-trick: exp monotone => exp(LR(z)-eM) = max(c1*E1[m], c2*E2[m]).
//    Inner body: 2 mul + max + (1+O) fma. No cmp/cndmask, no vcc chains.
//  * per-m data packed (E1,E2,W0,W1) in one float4 -> 1 ds_read_b128 per m
//    (+1 float2 for O=4), amortized over R=4 rows.
//  * reduction: slice-in-wave = lane&3 -> __shfl_xor(1,2) quad reduction (DPP),
//    then tiny padded cross-wave LDS buffer. LDS 19.7/29.6 KB -> 6/2 blocks/CU.
// All factors <= 1 (eM exact via LR monotonicity), den >= 1: no overflow.

#define GAT_ALPHA 0.2f
#define LOG2E 1.44269504088896f

template <int F, int O, int H, int RPB>
__global__ __launch_bounds__(256) void gat_layer_kernel(
    const float* __restrict__ x,            // (B, N, F)
    const float* __restrict__ Wt,           // (H, F, O)
    const float* __restrict__ at,           // (H, 2*O)
    float* __restrict__ out)                // (B, N, H*O)
{
    constexpr int N = 1024, NT = 256, S = 16;
    constexpr int R = RPB / 16;          // rows per thread
    constexpr int Q = O + 1;             // den + num[O]
    constexpr int CHUNKS = N / RPB;
    constexpr int PAD = R * Q + 1;       // bank-conflict-free per-r stride

    const int bid   = blockIdx.x;
    const int chunk = bid % CHUNKS;
    const int h     = (bid / CHUNKS) % H;
    const int b     = bid / (CHUNKS * H);
    const int tid   = threadIdx.x;
    const int wv    = tid >> 6;          // wave 0..3
    const int l     = tid & 63;
    const int r     = (l >> 2) & 15;     // row group 0..15
    const int sq    = l & 3;             // slice-in-wave (quad)
    const int s     = (wv << 2) | sq;    // global m-slice 0..15

    // Per-head weights (block-uniform -> scalar loads)
    float Wl[F][4];
#pragma unroll
    for (int f = 0; f < F; ++f)
#pragma unroll
        for (int o = 0; o < O; ++o) Wl[f][o] = Wt[(h * F + f) * O + o];
    float asrc[4], adst[4];
#pragma unroll
    for (int o = 0; o < O; ++o) {
        asrc[o] = at[h * 2 * O + o];
        adst[o] = at[h * 2 * O + O + o];
    }

    __shared__ float4 sEW[N];                  // staging: (d,0,W0,W1); after B: (E1,E2,W0,W1)
    __shared__ float2 sW2[(O > 2) ? N : 1];    // (W2,W3) for O=4
    __shared__ float  sred[4];
    __shared__ float  sredu[4 * 16 * PAD];

    // ---- Phase A: Wh + d for all m; block max D ----
    const float* xb = x + (size_t)b * N * F;
    float dmax = -3.0e38f;
    for (int m = tid; m < N; m += NT) {
        float xv[F];
        if constexpr (F == 4) {
            const float4 v = ((const float4*)xb)[m];
            xv[0] = v.x; xv[1] = v.y; xv[2] = v.z; xv[3] = v.w;
        } else {
#pragma unroll
            for (int k = 0; k < F / 2; ++k) {
                const float2 v = ((const float2*)xb)[m * (F / 2) + k];
                xv[2 * k] = v.x; xv[2 * k + 1] = v.y;
            }
        }
        float wh[4], d = 0.0f;
#pragma unroll
        for (int o = 0; o < O; ++o) {
            float acc = 0.0f;
#pragma unroll
            for (int f = 0; f < F; ++f) acc += xv[f] * Wl[f][o];
            wh[o] = acc; d += acc * adst[o];
        }
        sEW[m] = make_float4(d, 0.0f, wh[0], wh[1]);
        if constexpr (O > 2) sW2[m] = make_float2(wh[2], wh[3]);
        dmax = fmaxf(dmax, d);
    }
#pragma unroll
    for (int off = 32; off; off >>= 1) dmax = fmaxf(dmax, __shfl_xor(dmax, off, 64));
    if (l == 0) sred[wv] = dmax;
    __syncthreads();
    const float D = fmaxf(fmaxf(sred[0], sred[1]), fmaxf(sred[2], sred[3]));

    // ---- Per-row constants c1,c2 (one exp per row) ----
    float c1[R], c2[R];
#pragma unroll
    for (int j = 0; j < R; ++j) {
        const int row = chunk * RPB + r + 16 * j;
        const float4 ew = sEW[row];
        float sn = ew.z * asrc[0] + ew.w * asrc[1];
        if constexpr (O > 2) {
            const float2 w2 = sW2[row];
            sn += w2.x * asrc[2] + w2.y * asrc[3];
        }
        const float z = sn + D;
        const float e = __builtin_amdgcn_exp2f(-0.8f * LOG2E * fabsf(z));
        c1[j] = (z >= 0.0f) ? 1.0f : e;       // e^{sn+D-eM}
        c2[j] = (z >= 0.0f) ? e : 1.0f;       // e^{0.2(sn+D)-eM}
    }

    // ---- Phase B: own m's -> (E1,E2) into sEW.xy (no race: same-thread set) ----
    for (int m = tid; m < N; m += NT) {
        const float t = (sEW[m].x - D) * LOG2E;
        sEW[m].x = __builtin_amdgcn_exp2f(t);
        sEW[m].y = __builtin_amdgcn_exp2f(GAT_ALPHA * t);
    }
    __syncthreads();

    // ---- Inner loop: 1 b128 (+1 b64) per m, R rows, pure full-rate VALU ----
    float den[R], num[R][4];
#pragma unroll
    for (int j = 0; j < R; ++j) {
        den[j] = 0.0f;
#pragma unroll
        for (int o = 0; o < 4; ++o) num[j][o] = 0.0f;
    }

#pragma unroll 4
    for (int mi = 0; mi < N / S; ++mi) {
        const int m = mi * S + s;             // 4 consecutive m per quad -> conflict-free
        const float4 ew = sEW[m];
        float w2x = 0.0f, w2y = 0.0f;
        if constexpr (O > 2) { const float2 t2 = sW2[m]; w2x = t2.x; w2y = t2.y; }
#pragma unroll
        for (int j = 0; j < R; ++j) {
            const float wgt = fmaxf(c1[j] * ew.x, c2[j] * ew.y);
            den[j]    += wgt;
            num[j][0] += wgt * ew.z;
            num[j][1] += wgt * ew.w;
            if constexpr (O > 2) {
                num[j][2] += wgt * w2x;
                num[j][3] += wgt * w2y;
            }
        }
    }

    // ---- Quad (slice-in-wave) reduction via DPP shuffles ----
#pragma unroll
    for (int j = 0; j < R; ++j) {
        den[j] += __shfl_xor(den[j], 1, 64);
        den[j] += __shfl_xor(den[j], 2, 64);
#pragma unroll
        for (int o = 0; o < O; ++o) {
            num[j][o] += __shfl_xor(num[j][o], 1, 64);
            num[j][o] += __shfl_xor(num[j][o], 2, 64);
        }
    }
    if (sq == 0) {
#pragma unroll
        for (int j = 0; j < R; ++j) {
            const int base = (wv * 16 + r) * PAD + j * Q;
            sredu[base] = den[j];
#pragma unroll
            for (int o = 0; o < O; ++o) sredu[base + 1 + o] = num[j][o];
        }
    }
    __syncthreads();

    // ---- Cross-wave reduce + softmax divide + ELU + store ----
    for (int idx = tid; idx < RPB * O; idx += NT) {
        const int rowl = idx / O, o = idx % O;
        const int rr = rowl & 15, jj = rowl >> 4;
        float dn = 0.0f, nm = 0.0f;
#pragma unroll
        for (int ww = 0; ww < 4; ++ww) {
            const int base = (ww * 16 + rr) * PAD + jj * Q;
            dn += sredu[base];
            nm += sredu[base + 1 + o];
        }
        float v = nm / dn;                               // dn >= 1
        v = (v > 0.0f) ? v : (__expf(v) - 1.0f);         // ELU(alpha=1)
        const int row = chunk * RPB + rowl;
        out[((size_t)b * N + row) * (H * O) + h * O + o] = v;
    }
}

extern "C" void kernel_launch(void* const* d_in, const int* in_sizes, int n_in,
                              void* d_out, int out_size, void* d_ws, size_t ws_size,
                              hipStream_t stream) {
    const float* x  = (const float*)d_in[0];  // (32,1024,4)
    const float* W1 = (const float*)d_in[1];  // (3,4,2)
    const float* a1 = (const float*)d_in[2];  // (3,4,1)
    const float* W2 = (const float*)d_in[3];  // (1,6,4)
    const float* a2 = (const float*)d_in[4];  // (1,8,1)

    float* h1 = (float*)d_ws;     // (32,1024,6) fp32 = 768 KiB scratch
    float* y  = (float*)d_out;    // (32,1024,4) fp32

    constexpr int B = 32;
    // Layer 1: H=3,F=4,O=2, RPB=64 -> 1536 blocks (6/CU, LDS 19.7 KB)
    gat_layer_kernel<4, 2, 3, 64><<<B * 3 * 16, 256, 0, stream>>>(x, W1, a1, h1);
    // Layer 2: H=1,F=6,O=4, RPB=64 -> 512 blocks (2/CU, LDS 29.6 KB)
    gat_layer_kernel<6, 4, 1, 64><<<B * 1 * 16, 256, 0, stream>>>(h1, W2, a2, y);
}

// Round 7
// 85.727 us; speedup vs baseline: 1.1042x; 1.1042x over previous
//
#include <hip/hip_runtime.h>

// 2-layer dense GAT, B=32, N=1024, all fp32. L1: H=3,F=4,O=2 -> ws. L2: H=1,F=6,O=4 -> out.
//
// Round-7: VALU-issue reduction via packed fp32 (VOP3P v_pk_mul/add/fma_f32).
// Inner loop processes m-PAIRS (2q, 2q+1) with ext_vector_type(2) math:
// per (row, 2m): 2 pk_mul + 2 v_max + 1 pk_add + O pk_fma  (~1.7x fewer VALU).
// LDS pair-packed: sE[q]=(E1lo,E1hi,E2lo,E2hi), sW01[q]=(W0lo,W0hi,W1lo,W1hi).
// Exp stays hoisted (N exps): w = exp(LR(z)-eM) = max(c1*E1[m], c2*E2[m]),
// all factors <= 1 (eM exact via leaky-relu monotonicity), den >= 1.
// L1 uses R=8 rows/thread (RPB=128) to halve LDS-port issue; L2 R=4 (RPB=64).

#define GAT_ALPHA 0.2f
#define LOG2E 1.44269504088896f

typedef float v2f __attribute__((ext_vector_type(2)));

template <int F, int O, int H, int RPB>
__global__ __launch_bounds__(256) void gat_layer_kernel(
    const float* __restrict__ x,            // (B, N, F)
    const float* __restrict__ Wt,           // (H, F, O)
    const float* __restrict__ at,           // (H, 2*O)
    float* __restrict__ out)                // (B, N, H*O)
{
    constexpr int N = 1024, NT = 256, S = 16;
    constexpr int NP = N / 2;            // m-pairs
    constexpr int R = RPB / 16;          // rows per thread
    constexpr int Q = O + 1;             // den + num[O]
    constexpr int CHUNKS = N / RPB;
    constexpr int PAD = R * Q + 1;       // bank-conflict-free per-r stride

    const int bid   = blockIdx.x;
    const int chunk = bid % CHUNKS;
    const int h     = (bid / CHUNKS) % H;
    const int b     = bid / (CHUNKS * H);
    const int tid   = threadIdx.x;
    const int wv    = tid >> 6;          // wave 0..3
    const int l     = tid & 63;
    const int r     = (l >> 2) & 15;     // row group 0..15
    const int sq    = l & 3;             // slice-in-wave (quad)
    const int s     = (wv << 2) | sq;    // global pair-slice 0..15

    // Per-head weights (block-uniform -> scalar loads)
    float Wl[F][O];
#pragma unroll
    for (int f = 0; f < F; ++f)
#pragma unroll
        for (int o = 0; o < O; ++o) Wl[f][o] = Wt[(h * F + f) * O + o];
    float asrc[O], adst[O];
#pragma unroll
    for (int o = 0; o < O; ++o) {
        asrc[o] = at[h * 2 * O + o];
        adst[o] = at[h * 2 * O + O + o];
    }

    __shared__ float2 sd2[NP];                 // (d_lo, d_hi) per pair
    __shared__ float4 sE[NP];                  // (E1lo,E1hi,E2lo,E2hi)
    __shared__ float4 sW01[NP];                // (W0lo,W0hi,W1lo,W1hi)
    __shared__ float4 sW23[(O > 2) ? NP : 1];  // (W2lo,W2hi,W3lo,W3hi)
    __shared__ float  sred[4];
    __shared__ float  sredu[4 * 16 * PAD];

    // ---- Phase A: per pair q: Wh + d for rows 2q,2q+1; block max D ----
    const float* xb = x + (size_t)b * N * F;
    float dmax = -3.0e38f;
#pragma unroll
    for (int qq = 0; qq < NP / NT; ++qq) {
        const int q = qq * NT + tid;
        float xv[2][F];
        if constexpr (F == 4) {
            const float4 va = ((const float4*)xb)[2 * q];
            const float4 vb = ((const float4*)xb)[2 * q + 1];
            xv[0][0] = va.x; xv[0][1] = va.y; xv[0][2] = va.z; xv[0][3] = va.w;
            xv[1][0] = vb.x; xv[1][1] = vb.y; xv[1][2] = vb.z; xv[1][3] = vb.w;
        } else {  // F == 6: rows at 24 B; even row = f4+f2, odd row = f2+f4
            const float4* x4 = (const float4*)xb;
            const float2* x2 = (const float2*)xb;
            const float4 fa = x4[3 * q];         // row even [0..3]
            const float2 fb = x2[6 * q + 2];     // row even [4..5]
            const float2 fc = x2[6 * q + 3];     // row odd  [0..1]
            const float4 fd = x4[3 * q + 2];     // row odd  [2..5]
            xv[0][0] = fa.x; xv[0][1] = fa.y; xv[0][2] = fa.z; xv[0][3] = fa.w;
            xv[0][4] = fb.x; xv[0][5] = fb.y;
            xv[1][0] = fc.x; xv[1][1] = fc.y;
            xv[1][2] = fd.x; xv[1][3] = fd.y; xv[1][4] = fd.z; xv[1][5] = fd.w;
        }
        float wh[2][O], d[2];
#pragma unroll
        for (int p = 0; p < 2; ++p) {
            d[p] = 0.0f;
#pragma unroll
            for (int o = 0; o < O; ++o) {
                float acc = 0.0f;
#pragma unroll
                for (int f = 0; f < F; ++f) acc += xv[p][f] * Wl[f][o];
                wh[p][o] = acc; d[p] += acc * adst[o];
            }
        }
        sd2[q]  = make_float2(d[0], d[1]);
        sW01[q] = make_float4(wh[0][0], wh[1][0], wh[0][1], wh[1][1]);
        if constexpr (O > 2)
            sW23[q] = make_float4(wh[0][2], wh[1][2], wh[0][3], wh[1][3]);
        dmax = fmaxf(dmax, fmaxf(d[0], d[1]));
    }
#pragma unroll
    for (int off = 32; off; off >>= 1) dmax = fmaxf(dmax, __shfl_xor(dmax, off, 64));
    if (l == 0) sred[wv] = dmax;
    __syncthreads();
    const float D = fmaxf(fmaxf(sred[0], sred[1]), fmaxf(sred[2], sred[3]));

    // ---- Phase B: own pairs -> (E1,E2) packed (same-thread RAW, no barrier) ----
#pragma unroll
    for (int qq = 0; qq < NP / NT; ++qq) {
        const int q = qq * NT + tid;
        const float2 dp = sd2[q];
        const float t0 = (dp.x - D) * LOG2E;
        const float t1 = (dp.y - D) * LOG2E;
        sE[q] = make_float4(__builtin_amdgcn_exp2f(t0),
                            __builtin_amdgcn_exp2f(t1),
                            __builtin_amdgcn_exp2f(GAT_ALPHA * t0),
                            __builtin_amdgcn_exp2f(GAT_ALPHA * t1));
    }

    // ---- Per-row constants c1,c2 (one exp per row) ----
    float c1[R], c2[R];
#pragma unroll
    for (int j = 0; j < R; ++j) {
        const int row = chunk * RPB + r + 16 * j;
        const int qr = row >> 1, cp = row & 1;
        const float4 w01 = sW01[qr];
        float sn = (cp ? w01.y : w01.x) * asrc[0] + (cp ? w01.w : w01.z) * asrc[1];
        if constexpr (O > 2) {
            const float4 w23 = sW23[qr];
            sn += (cp ? w23.y : w23.x) * asrc[2] + (cp ? w23.w : w23.z) * asrc[3];
        }
        const float z = sn + D;
        const float e = __builtin_amdgcn_exp2f(-0.8f * LOG2E * fabsf(z));
        c1[j] = (z >= 0.0f) ? 1.0f : e;       // e^{sn+D-eM}
        c2[j] = (z >= 0.0f) ? e : 1.0f;       // e^{0.2(sn+D)-eM}
    }
    __syncthreads();                           // sE visible to all

    // ---- Inner loop: packed m-pairs, pure pk-VALU ----
    v2f den[R], num[R][O];
#pragma unroll
    for (int j = 0; j < R; ++j) {
        den[j] = (v2f)(0.0f);
#pragma unroll
        for (int o = 0; o < O; ++o) num[j][o] = (v2f)(0.0f);
    }

#pragma unroll 4
    for (int p = 0; p < NP / S; ++p) {
        const int q = p * S + s;               // 16 lanes broadcast, quad spans 4 addrs
        const float4 e4 = sE[q];
        const float4 w4 = sW01[q];
        const v2f E1 = {e4.x, e4.y}, E2 = {e4.z, e4.w};
        const v2f W0 = {w4.x, w4.y}, W1 = {w4.z, w4.w};
        v2f W2, W3;
        if constexpr (O > 2) {
            const float4 w4b = sW23[q];
            W2 = (v2f){w4b.x, w4b.y}; W3 = (v2f){w4b.z, w4b.w};
        }
#pragma unroll
        for (int j = 0; j < R; ++j) {
            const v2f A = c1[j] * E1;          // v_pk_mul_f32
            const v2f Bv = c2[j] * E2;         // v_pk_mul_f32
            v2f w;
            w.x = fmaxf(A.x, Bv.x);            // no pk-max on gfx9xx: 2x v_max_f32
            w.y = fmaxf(A.y, Bv.y);
            den[j] += w;                       // v_pk_add_f32
            num[j][0] += w * W0;               // v_pk_fma_f32
            num[j][1] += w * W1;
            if constexpr (O > 2) {
                num[j][2] += w * W2;
                num[j][3] += w * W3;
            }
        }
    }

    // ---- Collapse pair halves, quad (slice-in-wave) shuffle reduction ----
#pragma unroll
    for (int j = 0; j < R; ++j) {
        float dn = den[j].x + den[j].y;
        dn += __shfl_xor(dn, 1, 64);
        dn += __shfl_xor(dn, 2, 64);
        float nm[O];
#pragma unroll
        for (int o = 0; o < O; ++o) {
            nm[o] = num[j][o].x + num[j][o].y;
            nm[o] += __shfl_xor(nm[o], 1, 64);
            nm[o] += __shfl_xor(nm[o], 2, 64);
        }
        if (sq == 0) {
            const int base = (wv * 16 + r) * PAD + j * Q;
            sredu[base] = dn;
#pragma unroll
            for (int o = 0; o < O; ++o) sredu[base + 1 + o] = nm[o];
        }
    }
    __syncthreads();

    // ---- Cross-wave reduce + softmax divide + ELU + store ----
    for (int idx = tid; idx < RPB * O; idx += NT) {
        const int rowl = idx / O, o = idx % O;
        const int rr = rowl & 15, jj = rowl >> 4;
        float dn = 0.0f, nm = 0.0f;
#pragma unroll
        for (int ww = 0; ww < 4; ++ww) {
            const int base = (ww * 16 + rr) * PAD + jj * Q;
            dn += sredu[base];
            nm += sredu[base + 1 + o];
        }
        float v = nm / dn;                               // dn >= 1
        v = (v > 0.0f) ? v : (__expf(v) - 1.0f);         // ELU(alpha=1)
        const int row = chunk * RPB + rowl;
        out[((size_t)b * N + row) * (H * O) + h * O + o] = v;
    }
}

extern "C" void kernel_launch(void* const* d_in, const int* in_sizes, int n_in,
                              void* d_out, int out_size, void* d_ws, size_t ws_size,
                              hipStream_t stream) {
    const float* x  = (const float*)d_in[0];  // (32,1024,4)
    const float* W1 = (const float*)d_in[1];  // (3,4,2)
    const float* a1 = (const float*)d_in[2];  // (3,4,1)
    const float* W2 = (const float*)d_in[3];  // (1,6,4)
    const float* a2 = (const float*)d_in[4];  // (1,8,1)

    float* h1 = (float*)d_ws;     // (32,1024,6) fp32 = 768 KiB scratch
    float* y  = (float*)d_out;    // (32,1024,4) fp32

    constexpr int B = 32;
    // Layer 1: H=3,F=4,O=2, RPB=128 (R=8) -> 768 blocks (3/CU, LDS ~27 KB)
    gat_layer_kernel<4, 2, 3, 128><<<B * 3 * 8, 256, 0, stream>>>(x, W1, a1, h1);
    // Layer 2: H=1,F=6,O=4, RPB=64 (R=4) -> 512 blocks (2/CU, LDS ~34 KB)
    gat_layer_kernel<6, 4, 1, 64><<<B * 1 * 16, 256, 0, stream>>>(h1, W2, a2, y);
}